// Round 6
// baseline (149.102 us; speedup 1.0000x reference)
//
#include <hip/hip_runtime.h>
#include <math.h>

// S4 Vandermonde kernel: K[h,l] = 2*Re( sum_n Ct[h,n] * exp(dtA[h,n])^l )
//   dt  = exp(log_dt);  A = -exp(log_A_real) - i*A_imag;  dtA = A*dt
//   Ct  = C * (exp(dtA)-1) / A
// H=1024, NH=32, L=4096 (fixed).
//
// ROUND-6 = DIAGNOSTIC: the r5 kernel VERBATIM, launched 4x back-to-back
// (idempotent: every output element is unconditionally rewritten each
// launch). Purpose: separate harness fixed overhead OH from kernel time k:
//   r5:  OH + k  = 84.7 us
//   r6:  OH + 4k = dur_us (this round)
// Four structurally different kernels (r2-r5) all inferred ~24-27 us under
// the OH=59.7 assumption -- work-independent, so either OH is really ~80
// and k ~5 (harness floor reached), or something structural costs 20 us.
// This round decides.

#define HH 1024
#define NH 32
#define LL 4096
#define BLOCK 512
#define KCH 8
#define STRIDE 512

#define TWO_PI 6.28318530717958647692f
#define INV_TWO_PI 0.15915494309189533577f

__device__ __forceinline__ float sin_rev(float r) {  // r in [0,1) revolutions
    float d;
    asm("v_sin_f32 %0, %1" : "=v"(d) : "v"(r));
    return d;
}
__device__ __forceinline__ float cos_rev(float r) {
    float d;
    asm("v_cos_f32 %0, %1" : "=v"(d) : "v"(r));
    return d;
}

__global__ __launch_bounds__(BLOCK) void s4_vandermonde(
    const float* __restrict__ C,            // [H][NH][2]
    const float* __restrict__ log_dt,       // [H]
    const float* __restrict__ log_A_real,   // [H][NH]
    const float* __restrict__ A_imag,       // [H][NH]
    float* __restrict__ out)                // [H][LL]
{
    __shared__ float2 sW16[NH][32];  // 2*Ct*exp(dtA*16a), a<32
    __shared__ float2 sW1[NH][16];   // exp(dtA*b), b<16
    __shared__ float4 sP[NH];        // {re, Wr, Wi, bS=|W|^2}
    __shared__ float4 sAux[NH];      // {fm, ctr, cti, re}

    const int h = blockIdx.x;
    const int t = threadIdx.x;

    // ---- phase 0: per-n scalars (lanes 0..31) ----
    if (t < NH) {
        const int n = t;
        const float dt  = __expf(log_dt[h]);
        const float Are = -__expf(log_A_real[h * NH + n]);
        const float Aim = -A_imag[h * NH + n];
        const float re = Are * dt;               // Re(dtA), negative
        const float im = Aim * dt;               // Im(dtA)
        float s1, c1;
        __sincosf(im, &s1, &c1);
        const float er1 = __expf(re);
        const float X = er1 * c1 - 1.0f;
        const float Y = er1 * s1;
        const float C0 = C[(h * NH + n) * 2 + 0];
        const float C1 = C[(h * NH + n) * 2 + 1];
        const float nr = C0 * X - C1 * Y;
        const float ni = C0 * Y + C1 * X;
        const float inv = 2.0f / (Are * Are + Aim * Aim);  // folds final x2
        const float ctr = (nr * Are + ni * Aim) * inv;
        const float cti = (ni * Are - nr * Aim) * inv;
        const float fm = im * INV_TWO_PI;        // revolutions per unit l

        // W = exp(dtA * 512), double-precision phase reduction
        const float erS = __expf(re * 512.0f);   // underflows cleanly to 0
        double revd = (double)fm * 512.0;
        revd -= floor(revd);
        float sS, cS;
        __sincosf((float)revd * TWO_PI, &sS, &cS);

        sP[n]   = make_float4(re, erS * cS, erS * sS, erS * erS);
        sAux[n] = make_float4(fm, ctr, cti, re);
    }
    __syncthreads();

    // ---- phase 1: build tables. 32n*(16+32)=1536 entries, 3 per thread ----
#pragma unroll
    for (int q = 0; q < 3; ++q) {
        const int idx = t + q * BLOCK;           // [0,1536)
        const int n = idx / 48;
        const int j = idx - n * 48;              // [0,48)
        const float4 aux = sAux[n];
        const float fm = aux.x, ctr = aux.y, cti = aux.z, re = aux.w;
        if (j < 16) {
            const float m = (float)j;            // W1[j] = exp(dtA*j)
            const float er = __expf(re * m);
            float rev = fm * m;
            rev -= floorf(rev);
            sW1[n][j] = make_float2(er * cos_rev(rev), er * sin_rev(rev));
        } else {
            const int a = j - 16;                // W16'[a] = 2Ct*exp(dtA*16a)
            const float m = (float)(a * 16);
            const float er = __expf(re * m);
            float rev = fm * m;
            rev -= floorf(rev);
            const float br = er * cos_rev(rev);
            const float bi = er * sin_rev(rev);
            sW16[n][a] = make_float2(ctr * br - cti * bi, ctr * bi + cti * br);
        }
    }
    __syncthreads();

    // ---- main loop ----
    float acc[KCH];
#pragma unroll
    for (int k = 0; k < KCH; ++k) acc[k] = 0.0f;

    const float wminf = (float)(t & ~63);        // wave's min l (uniform)
    const int hi = t >> 4, lo = t & 15;

    for (int n = 0; n < NH; ++n) {
        const float4 P = sP[n];                  // broadcast b128
        if (P.x * wminf < -16.0f) continue;      // wave-uniform skip
        const float2 a2 = sW16[n][hi];
        const float2 b2 = sW1[n][lo];
        const float vr = a2.x * b2.x - a2.y * b2.y;  // V = 2Ct*exp(dtA*t)
        const float vi = a2.x * b2.y + a2.y * b2.x;
        float u0 = vr;                           // Re(V*W^0)
        float u1 = vr * P.y - vi * P.z;          // Re(V*W^1)
        acc[0] += u0;
        acc[1] += u1;
        const float aS = P.y + P.y;              // 2*Re(W)
#pragma unroll
        for (int k = 2; k < KCH; ++k) {
            const float u2 = aS * u1 - P.w * u0;
            acc[k] += u2;
            u0 = u1; u1 = u2;
        }
    }

    float* o = out + h * LL + t;
#pragma unroll
    for (int k = 0; k < KCH; ++k) o[k * STRIDE] = acc[k];
}

extern "C" void kernel_launch(void* const* d_in, const int* in_sizes, int n_in,
                              void* d_out, int out_size, void* d_ws, size_t ws_size,
                              hipStream_t stream) {
    const float* C          = (const float*)d_in[0];   // [1024][32][2]
    const float* log_dt     = (const float*)d_in[1];   // [1024]
    const float* log_A_real = (const float*)d_in[2];   // [1024][32]
    const float* A_imag     = (const float*)d_in[3];   // [1024][32]
    float* out              = (float*)d_out;           // [1024][4096]

    // DIAGNOSTIC: 4 identical idempotent launches -> dur_us = OH + 4k.
    // Combined with round-5 (OH + k = 84.7 us) this solves OH and k exactly.
    for (int rep = 0; rep < 4; ++rep) {
        s4_vandermonde<<<dim3(HH), dim3(BLOCK), 0, stream>>>(
            C, log_dt, log_A_real, A_imag, out);
    }
}

// Round 7
// 104.468 us; speedup vs baseline: 1.4273x; 1.4273x over previous
//
#include <hip/hip_runtime.h>
#include <math.h>

// S4 Vandermonde kernel: K[h,l] = 2*Re( sum_n Ct[h,n] * exp(dtA[h,n])^l )
//   dt  = exp(log_dt);  A = -exp(log_A_real) - i*A_imag;  dtA = A*dt
//   Ct  = C * (exp(dtA)-1) / A
// H=1024, NH=32, L=4096 (fixed).
//
// Round-7: WORK-STEALING over (h, l-half) items.
// Diagnosis (r5/r6 algebra + r1 counters): kernel ~21.5 us regardless of
// inner-loop work; r1 showed Occupancy 21% / VALUBusy 32% = tail-dominated.
// Grid was exactly resident with no refill and per-h cost varies ~10x, so
// duration = worst-CU straggler, not total work.
// Fix: 1024 resident blocks pull 2048 items (h, half) from a global atomic
// queue; heavy items (half0, contains l=0) are queued FIRST (LPT). Per item:
//  - phase 0 (lanes 0..31): per-n scalars; ballot detects all-dead items
//    (heavy h, high half) -> write zeros, next item.
//  - phase 1: LDS tables W16'[a]=2Ct*exp(dtA*(l0+16a)) (a<32, double phase
//    reduction), W1[b]=exp(dtA*b) (b<16) -> V = W16'[t>>4]*W1[t&15] with no
//    per-thread transcendentals.
//  - main: 4 outputs l = l0+t+512k via 2nd-order real recurrence
//    u_k = 2Re(W) u_{k-1} - |W|^2 u_{k-2}, W = exp(dtA*512) (double-reduced).
//  - wave-uniform gate: skip n when re*(l0 + (t&~63)) < -16 (term < 1.1e-7,
//    threshold 2.6e-2).

#define HH 1024
#define NH 32
#define LL 4096
#define BLOCK 512
#define NITEMS (2 * HH)
#define KCH 4
#define STRIDE 512

#define TWO_PI 6.28318530717958647692f
#define INV_TWO_PI 0.15915494309189533577f

__device__ __forceinline__ float sin_rev(float r) {  // r in [0,1) revolutions
    float d;
    asm("v_sin_f32 %0, %1" : "=v"(d) : "v"(r));
    return d;
}
__device__ __forceinline__ float cos_rev(float r) {
    float d;
    asm("v_cos_f32 %0, %1" : "=v"(d) : "v"(r));
    return d;
}

__global__ __launch_bounds__(BLOCK) void s4_vandermonde(
    const float* __restrict__ C,            // [H][NH][2]
    const float* __restrict__ log_dt,       // [H]
    const float* __restrict__ log_A_real,   // [H][NH]
    const float* __restrict__ A_imag,       // [H][NH]
    float* __restrict__ out,                // [H][LL]
    int* __restrict__ gctr)                 // zeroed queue counter
{
    __shared__ float2 sW16[NH][32];  // 2*Ct*exp(dtA*(l0+16a))
    __shared__ float2 sW1[NH][16];   // exp(dtA*b)
    __shared__ float4 sP[NH];        // {re, Wr, Wi, |W|^2}
    __shared__ float4 sAux[NH];      // {fm, ctr, cti, re}
    __shared__ int sIdx;
    __shared__ int sDead;

    const int t = threadIdx.x;
    const int hi = t >> 4, lo = t & 15;

    for (;;) {
        if (t == 0) sIdx = atomicAdd(gctr, 1);
        __syncthreads();                      // sIdx visible; LDS safe to reuse
        const int item = sIdx;
        if (item >= NITEMS) break;            // uniform exit
        const int half = (item < HH) ? 0 : 1; // heavy halves (l0=0) first
        const int h    = (item < HH) ? item : item - HH;
        const int l0   = half * 2048;
        const float l0f = (float)l0;

        // ---- phase 0: per-n scalars (lanes 0..31 of wave 0) ----
        bool aliveLane = false;
        if (t < NH) {
            const int n = t;
            const float dt  = __expf(log_dt[h]);
            const float Are = -__expf(log_A_real[h * NH + n]);
            const float Aim = -A_imag[h * NH + n];
            const float re = Are * dt;               // Re(dtA), negative
            const float im = Aim * dt;               // Im(dtA)
            float s1, c1;
            __sincosf(im, &s1, &c1);
            const float er1 = __expf(re);
            const float X = er1 * c1 - 1.0f;
            const float Y = er1 * s1;
            const float C0 = C[(h * NH + n) * 2 + 0];
            const float C1 = C[(h * NH + n) * 2 + 1];
            const float nr = C0 * X - C1 * Y;
            const float ni = C0 * Y + C1 * X;
            const float inv = 2.0f / (Are * Are + Aim * Aim);  // folds x2
            const float ctr = (nr * Are + ni * Aim) * inv;
            const float cti = (ni * Are - nr * Aim) * inv;
            const float fm = im * INV_TWO_PI;        // revolutions per unit l

            // W = exp(dtA * 512), double-precision phase reduction
            const float erS = __expf(re * 512.0f);   // underflows cleanly
            double revd = (double)fm * 512.0;
            revd -= floor(revd);
            float sS, cS;
            __sincosf((float)revd * TWO_PI, &sS, &cS);

            sP[n]   = make_float4(re, erS * cS, erS * sS, erS * erS);
            sAux[n] = make_float4(fm, ctr, cti, re);
            aliveLane = (re * l0f > -16.0f);         // survives at item's l0?
        }
        const unsigned long long bal = __ballot(aliveLane);
        if (t == 0) sDead = (bal == 0ull) ? 1 : 0;
        __syncthreads();

        if (sDead) {                                  // uniform
            float* o = out + h * LL + l0 + t;
#pragma unroll
            for (int k = 0; k < KCH; ++k) o[k * STRIDE] = 0.0f;
            continue;
        }

        // ---- phase 1: tables, 1536 entries, 3 per thread ----
#pragma unroll
        for (int q = 0; q < 3; ++q) {
            const int idx = t + q * BLOCK;           // [0,1536)
            const int n = idx / 48;
            const int j = idx - n * 48;              // [0,48)
            const float4 aux = sAux[n];
            const float fm = aux.x, ctr = aux.y, cti = aux.z, re = aux.w;
            if (j < 16) {
                const float m = (float)j;            // W1[j] = exp(dtA*j)
                const float er = __expf(re * m);
                float rev = fm * m;
                rev -= floorf(rev);
                sW1[n][j] = make_float2(er * cos_rev(rev), er * sin_rev(rev));
            } else {
                const int a = j - 16;                // W16'[a]=2Ct*e^{dtA*(l0+16a)}
                const float m = (float)(l0 + a * 16);
                const float er = __expf(re * m);     // underflow -> 0 ok
                double revd = (double)fm * (double)m;
                revd -= floor(revd);
                const float rev = (float)revd;
                const float br = er * cos_rev(rev);
                const float bi = er * sin_rev(rev);
                sW16[n][a] = make_float2(ctr * br - cti * bi,
                                         ctr * bi + cti * br);
            }
        }
        __syncthreads();

        // ---- main loop ----
        float acc[KCH];
#pragma unroll
        for (int k = 0; k < KCH; ++k) acc[k] = 0.0f;

        const float wminf = (float)(l0 + (t & ~63)); // wave's min l (uniform)

        for (int n = 0; n < NH; ++n) {
            const float4 P = sP[n];                  // broadcast b128
            if (P.x * wminf >= -16.0f) {             // wave-uniform gate
                const float2 a2 = sW16[n][hi];
                const float2 b2 = sW1[n][lo];
                const float vr = a2.x * b2.x - a2.y * b2.y;  // V
                const float vi = a2.x * b2.y + a2.y * b2.x;
                float u0 = vr;                       // Re(V*W^0)
                float u1 = vr * P.y - vi * P.z;      // Re(V*W^1)
                acc[0] += u0;
                acc[1] += u1;
                const float aS = P.y + P.y;          // 2*Re(W)
#pragma unroll
                for (int k = 2; k < KCH; ++k) {
                    const float u2 = aS * u1 - P.w * u0;
                    acc[k] += u2;
                    u0 = u1; u1 = u2;
                }
            }
        }

        float* o = out + h * LL + l0 + t;
#pragma unroll
        for (int k = 0; k < KCH; ++k) o[k * STRIDE] = acc[k];
    }
}

extern "C" void kernel_launch(void* const* d_in, const int* in_sizes, int n_in,
                              void* d_out, int out_size, void* d_ws, size_t ws_size,
                              hipStream_t stream) {
    const float* C          = (const float*)d_in[0];   // [1024][32][2]
    const float* log_dt     = (const float*)d_in[1];   // [1024]
    const float* log_A_real = (const float*)d_in[2];   // [1024][32]
    const float* A_imag     = (const float*)d_in[3];   // [1024][32]
    float* out              = (float*)d_out;           // [1024][4096]
    int* gctr               = (int*)d_ws;              // queue counter

    hipMemsetAsync(gctr, 0, sizeof(int), stream);      // d_ws is 0xAA-poisoned
    s4_vandermonde<<<dim3(HH), dim3(BLOCK), 0, stream>>>(
        C, log_dt, log_A_real, A_imag, out, gctr);
}

// Round 8
// 83.717 us; speedup vs baseline: 1.7810x; 1.2479x over previous
//
#include <hip/hip_runtime.h>
#include <math.h>

// S4 Vandermonde kernel: K[h,l] = 2*Re( sum_n Ct[h,n] * exp(dtA[h,n])^l )
//   dt  = exp(log_dt);  A = -exp(log_A_real) - i*A_imag;  dtA = A*dt
//   Ct  = C * (exp(dtA)-1) / A
// H=1024, NH=32, L=4096 (fixed).
//
// Round-8: r7's LPT schedule with the ATOMIC CONTENTION removed.
// r7 regressed (+19 us) because 2048 device-scope atomicAdds on ONE
// cacheline from 8 XCDs serialized at the coherence point while every
// block barrier-waited on the result (thundering herd at kernel start).
// Fix, schedule otherwise identical:
//   - block b's FIRST item is heavy item b (h=b, l0=0): static, no atomic.
//   - only the 1024 light items (l0=2048) are stolen, from 8 partitioned
//     counters 256 B apart (partition p = blockIdx&7 ~ XCD-local; light
//     item = 1024 + p + 8*j, j = atomicAdd of partition counter, j<128).
//     Steals are time-staggered (after each block's heavy item) and spread
//     over 8 lines -> negligible contention.
// Per item (unchanged from r7): phase0 scalars (lanes<32) + dead-item
// ballot (light items of fast-decay h -> write zeros); LDS tables
// W16'[a]=2Ct*exp(dtA*(l0+16a)) (32/n, double-reduced phase),
// W1[b]=exp(dtA*b) (16/n); 4 outputs l=l0+t+512k via 2nd-order real
// recurrence u_k = 2Re(W)u_{k-1} - |W|^2 u_{k-2}, W=exp(dtA*512);
// wave-uniform gate re*(l0+(t&~63)) < -16 skips dead n.

#define HH 1024
#define NH 32
#define LL 4096
#define BLOCK 512
#define KCH 4
#define STRIDE 512
#define NPART 8
#define PART_ITEMS (HH / NPART)    // 128 light items per partition
#define CTR_STRIDE 64              // ints: 256 B between counters

#define TWO_PI 6.28318530717958647692f
#define INV_TWO_PI 0.15915494309189533577f

__device__ __forceinline__ float sin_rev(float r) {  // r in [0,1) revolutions
    float d;
    asm("v_sin_f32 %0, %1" : "=v"(d) : "v"(r));
    return d;
}
__device__ __forceinline__ float cos_rev(float r) {
    float d;
    asm("v_cos_f32 %0, %1" : "=v"(d) : "v"(r));
    return d;
}

__global__ __launch_bounds__(BLOCK) void s4_vandermonde(
    const float* __restrict__ C,            // [H][NH][2]
    const float* __restrict__ log_dt,       // [H]
    const float* __restrict__ log_A_real,   // [H][NH]
    const float* __restrict__ A_imag,       // [H][NH]
    float* __restrict__ out,                // [H][LL]
    int* __restrict__ q)                    // 8 zeroed counters, 256B apart
{
    __shared__ float2 sW16[NH][32];  // 2*Ct*exp(dtA*(l0+16a))
    __shared__ float2 sW1[NH][16];   // exp(dtA*b)
    __shared__ float4 sP[NH];        // {re, Wr, Wi, |W|^2}
    __shared__ float4 sAux[NH];      // {fm, ctr, cti, re}
    __shared__ int sIdx;
    __shared__ int sDead;

    const int t = threadIdx.x;
    const int hi = t >> 4, lo = t & 15;
    const int p = blockIdx.x & (NPART - 1);
    int* pctr = q + p * CTR_STRIDE;

    int item = blockIdx.x;                   // static first item: heavy half
    for (;;) {
        const int half = (item < HH) ? 0 : 1;
        const int h    = (item < HH) ? item : item - HH;
        const int l0   = half * 2048;
        const float l0f = (float)l0;

        // ---- phase 0: per-n scalars (lanes 0..31 of wave 0) ----
        bool aliveLane = false;
        if (t < NH) {
            const int n = t;
            const float dt  = __expf(log_dt[h]);
            const float Are = -__expf(log_A_real[h * NH + n]);
            const float Aim = -A_imag[h * NH + n];
            const float re = Are * dt;               // Re(dtA), negative
            const float im = Aim * dt;               // Im(dtA)
            float s1, c1;
            __sincosf(im, &s1, &c1);
            const float er1 = __expf(re);
            const float X = er1 * c1 - 1.0f;
            const float Y = er1 * s1;
            const float C0 = C[(h * NH + n) * 2 + 0];
            const float C1 = C[(h * NH + n) * 2 + 1];
            const float nr = C0 * X - C1 * Y;
            const float ni = C0 * Y + C1 * X;
            const float inv = 2.0f / (Are * Are + Aim * Aim);  // folds x2
            const float ctr = (nr * Are + ni * Aim) * inv;
            const float cti = (ni * Are - nr * Aim) * inv;
            const float fm = im * INV_TWO_PI;        // revolutions per unit l

            // W = exp(dtA * 512), double-precision phase reduction
            const float erS = __expf(re * 512.0f);   // underflows cleanly
            double revd = (double)fm * 512.0;
            revd -= floor(revd);
            float sS, cS;
            __sincosf((float)revd * TWO_PI, &sS, &cS);

            sP[n]   = make_float4(re, erS * cS, erS * sS, erS * erS);
            sAux[n] = make_float4(fm, ctr, cti, re);
            aliveLane = (re * l0f > -16.0f);         // survives at item's l0?
        }
        const unsigned long long bal = __ballot(aliveLane);
        if (t == 0) sDead = (bal == 0ull) ? 1 : 0;
        __syncthreads();

        if (sDead) {                                  // uniform
            float* o = out + h * LL + l0 + t;
#pragma unroll
            for (int k = 0; k < KCH; ++k) o[k * STRIDE] = 0.0f;
        } else {
            // ---- phase 1: tables, 1536 entries, 3 per thread ----
#pragma unroll
            for (int qq = 0; qq < 3; ++qq) {
                const int idx = t + qq * BLOCK;          // [0,1536)
                const int n = idx / 48;
                const int j = idx - n * 48;              // [0,48)
                const float4 aux = sAux[n];
                const float fm = aux.x, ctr = aux.y, cti = aux.z, re = aux.w;
                if (j < 16) {
                    const float m = (float)j;            // W1[j] = exp(dtA*j)
                    const float er = __expf(re * m);
                    float rev = fm * m;
                    rev -= floorf(rev);
                    sW1[n][j] = make_float2(er * cos_rev(rev),
                                            er * sin_rev(rev));
                } else {
                    const int a = j - 16;        // W16'[a]=2Ct*e^{dtA(l0+16a)}
                    const float m = (float)(l0 + a * 16);
                    const float er = __expf(re * m);     // underflow -> 0 ok
                    double revd = (double)fm * (double)m;
                    revd -= floor(revd);
                    const float rev = (float)revd;
                    const float br = er * cos_rev(rev);
                    const float bi = er * sin_rev(rev);
                    sW16[n][a] = make_float2(ctr * br - cti * bi,
                                             ctr * bi + cti * br);
                }
            }
            __syncthreads();

            // ---- main loop ----
            float acc[KCH];
#pragma unroll
            for (int k = 0; k < KCH; ++k) acc[k] = 0.0f;

            const float wminf = (float)(l0 + (t & ~63));

            for (int n = 0; n < NH; ++n) {
                const float4 P = sP[n];                  // broadcast b128
                if (P.x * wminf >= -16.0f) {             // wave-uniform gate
                    const float2 a2 = sW16[n][hi];
                    const float2 b2 = sW1[n][lo];
                    const float vr = a2.x * b2.x - a2.y * b2.y;
                    const float vi = a2.x * b2.y + a2.y * b2.x;
                    float u0 = vr;                       // Re(V*W^0)
                    float u1 = vr * P.y - vi * P.z;      // Re(V*W^1)
                    acc[0] += u0;
                    acc[1] += u1;
                    const float aS = P.y + P.y;          // 2*Re(W)
#pragma unroll
                    for (int k = 2; k < KCH; ++k) {
                        const float u2 = aS * u1 - P.w * u0;
                        acc[k] += u2;
                        u0 = u1; u1 = u2;
                    }
                }
            }

            float* o = out + h * LL + l0 + t;
#pragma unroll
            for (int k = 0; k < KCH; ++k) o[k * STRIDE] = acc[k];
        }

        // ---- steal next light item from this block's partition ----
        __syncthreads();                         // LDS reuse + store done
        if (t == 0) {
            const int j = atomicAdd(pctr, 1);
            sIdx = (j < PART_ITEMS) ? (HH + p + NPART * j) : -1;
        }
        __syncthreads();
        if (sIdx < 0) break;                     // uniform exit
        item = sIdx;
    }
}

extern "C" void kernel_launch(void* const* d_in, const int* in_sizes, int n_in,
                              void* d_out, int out_size, void* d_ws, size_t ws_size,
                              hipStream_t stream) {
    const float* C          = (const float*)d_in[0];   // [1024][32][2]
    const float* log_dt     = (const float*)d_in[1];   // [1024]
    const float* log_A_real = (const float*)d_in[2];   // [1024][32]
    const float* A_imag     = (const float*)d_in[3];   // [1024][32]
    float* out              = (float*)d_out;           // [1024][4096]
    int* q                  = (int*)d_ws;              // partition counters

    hipMemsetAsync(q, 0, NPART * CTR_STRIDE * sizeof(int), stream);
    s4_vandermonde<<<dim3(HH), dim3(BLOCK), 0, stream>>>(
        C, log_dt, log_A_real, A_imag, out, q);
}